// Round 17
// baseline (134.042 us; speedup 1.0000x reference)
//
#include <hip/hip_runtime.h>
#include <hip/hip_bf16.h>
#include <math.h>

#define NTOT 16384
#define HDIM 256
#define BBATCH 4
#define NSEQ 4096
#define FDIM 256
#define NE 262144
#define NEE (NE + NTOT)
#define NLAYER 3
#define LN_EPS 1e-5f
#define SLOPE 0.2f
#define CAP 64   // bucket capacity; deg ~ Poisson(17), overflow prob ~1e-13

typedef __attribute__((ext_vector_type(8))) short bf16x8;
typedef __attribute__((ext_vector_type(4))) float f32x4;

#define LDW 80    // gemm LDS row stride bytes
#define SLDW 72   // conv slab/B row stride bytes (18-word stride -> 2-way alias max, free)

// ---- workspace layout (bytes) ----
#define OFF_HA   0u          // ushort[NTOT*256]   8388608
#define OFF_HW   8388608u    // ushort[NTOT*256]   8388608
#define OFF_WC   16777216u   // ushort[256*768]    393216
#define OFF_WL   17170432u   // ushort[3*256*256]  393216
#define OFF_SP   17563648u   // float[4*NTOT]      262144
#define OFF_DP   17825792u   // float[4*NTOT]      262144
#define OFF_CNT  18087936u   // int[NTOT]          65536
#define OFF_CSR  18153472u   // int[NTOT*CAP]      4194304
#define OFF_WT   22347776u   // float[3*256*256]   786432
#define OFF_F1   23134208u   // int[NTOT] flag level-1
#define OFF_F2   23199744u   // int[NTOT] flag level-2
#define OFF_L1   23265280u   // int[NTOT] list S1
#define OFF_L2   23330816u   // int[NTOT] list S2
#define OFF_CT   23396352u   // int[2]: ct[0]=|S2|, ct[1]=|S1|

static __device__ __forceinline__ unsigned short f2b(float f) {
    __hip_bfloat16 h = __float2bfloat16(f);
    return __builtin_bit_cast(unsigned short, h);
}
static __device__ __forceinline__ float b2f(unsigned short u) {
    __hip_bfloat16 h = __builtin_bit_cast(__hip_bfloat16, u);
    return __bfloat162float(h);
}
static __device__ __forceinline__ float rlanef(float v, int l) {
    return __builtin_bit_cast(float, __builtin_amdgcn_readlane(__builtin_bit_cast(int, v), l));
}

// wave-aggregated list append: one atomicAdd per wave, plain stores.
static __device__ __forceinline__ void wave_append(bool isNew, int src, int lane,
                                                   int* ctp, int* list) {
    unsigned long long mask = __ballot(isNew);
    int base = 0;
    if (lane == 0 && mask) base = atomicAdd(ctp, (int)__popcll(mask));
    base = __shfl(base, 0);
    if (isNew) {
        int off = (int)__popcll(mask & ((1ull << lane) - 1ull));
        list[base + off] = src;
    }
}

// ---- pre-pass: weight prep + zero cnt/flags/ctrs ----
__global__ __launch_bounds__(256) void k_pre(const float* __restrict__ tcw, const float* __restrict__ gatW,
                                             unsigned short* __restrict__ wcB, unsigned short* __restrict__ WTb,
                                             float* __restrict__ wT, int* __restrict__ cnt,
                                             int* __restrict__ flag1, int* __restrict__ flag2,
                                             int* __restrict__ ct) {
    int b = blockIdx.x, t = threadIdx.x;
    if (b < 256) {
        const float* s = tcw + b * 768 + t * 3;
        wcB[b * 768 + 0 + t]   = f2b(s[0]);
        wcB[b * 768 + 256 + t] = f2b(s[1]);
        wcB[b * 768 + 512 + t] = f2b(s[2]);
    } else if (b < 1024) {
        int ln = b - 256; int n = ln & 255; int l = ln >> 8;
        WTb[(size_t)l * 65536 + n * 256 + t] = f2b(gatW[(size_t)l * 65536 + t * 256 + n]);
    } else if (b < 1792) {
        int fk = b - 1024; int f = fk / 3, k = fk - 3 * f;
        wT[(k * FDIM + f) * HDIM + t] = tcw[t * 768 + fk];
    } else if (b < 1808) {
        int i = ((b - 1792) * 256 + t) * 4;
        *(int4*)(cnt + i) = make_int4(0, 0, 0, 0);
    } else if (b < 1824) {
        int i = ((b - 1808) * 256 + t) * 4;
        *(int4*)(flag1 + i) = make_int4(0, 0, 0, 0);
    } else if (b < 1840) {
        int i = ((b - 1824) * 256 + t) * 4;
        *(int4*)(flag2 + i) = make_int4(0, 0, 0, 0);
    } else {
        if (t < 2) ct[t] = 0;
    }
}

// ---------------- conv GEMM BM=64 x full-N (halo slab staged ONCE per K-step, all 4
// col-quarters computed by the same block — removes round-12's 4x slab redundancy and
// doubles per-barrier MFMA density) + bucket SCATTER + S2 build ----------------
// grid (64+272, 4): x<64 -> strip = x*4+y (256 strips of 64 rows); x>=64 -> scatter slice.
__global__ __launch_bounds__(256) void k_conv(const float* __restrict__ x,
                                              const unsigned short* __restrict__ wcB,
                                              const float* __restrict__ tcb,
                                              unsigned short* __restrict__ hAb,
                                              const int* __restrict__ ei, int* __restrict__ cnt,
                                              int* __restrict__ csr,
                                              int* __restrict__ flag2, int* __restrict__ list2,
                                              int* __restrict__ ct) {
    __shared__ char slab[66 * SLDW];        // 4752 B
    __shared__ char Bs[3 * 256 * SLDW];     // 55296 B  (total 60048 <= 64KB)
    int t = threadIdx.x;
    if (blockIdx.x >= 64) {   // bucket scatter + S2 detection
        int cid = (blockIdx.x - 64) * 4 + blockIdx.y;   // 0..1087
        int e = cid * 256 + t;
        int src, dst;
        if (e < NE) { src = ei[e]; dst = ei[NE + e]; } else { src = dst = e - NE; }
        int slot = atomicAdd(&cnt[dst], 1);
        if (slot < CAP) csr[dst * CAP + slot] = src;
        bool isNew = false;
        if ((dst & 4095) < 2) isNew = (atomicExch(&flag2[src], 1) == 0);
        wave_append(isNew, src, t & 63, &ct[0], list2);
        return;
    }
    int m0 = (blockIdx.x * 4 + blockIdx.y) * 64;
    int bb = m0 >> 12;
    int nloc0 = m0 & 4095;
    int w = t >> 6, lane = t & 63;
    int row16 = lane & 15, kg = lane >> 4;
    f32x4 acc[4][4];
    #pragma unroll
    for (int mi = 0; mi < 4; ++mi)
        #pragma unroll
        for (int ni = 0; ni < 4; ++ni) acc[mi][ni] = (f32x4)(0.f);

    for (int kb = 0; kb < 8; ++kb) {
        int c0 = kb * 32;
        __syncthreads();   // previous step's MFMA reads complete before overwrite
        {   // slab rows 0..63: 4 threads/row, 8 fp32 (32B) -> 16B bf16 each
            int r = t >> 2, u = t & 3;
            int nl = nloc0 - 1 + r;
            ushort4 o0 = make_ushort4(0,0,0,0), o1 = make_ushort4(0,0,0,0);
            if ((unsigned)nl < 4096u) {
                const float4* s = (const float4*)(x + ((size_t)(bb << 12) + nl) * 256 + c0 + u * 8);
                float4 f0 = s[0], f1 = s[1];
                o0 = make_ushort4(f2b(f0.x), f2b(f0.y), f2b(f0.z), f2b(f0.w));
                o1 = make_ushort4(f2b(f1.x), f2b(f1.y), f2b(f1.z), f2b(f1.w));
            }
            char* d = &slab[r * SLDW + u * 16];
            *(ushort4*)(d)     = o0;
            *(ushort4*)(d + 8) = o1;
        }
        if (t < 8) {   // slab rows 64,65
            int r = 64 + (t >> 2), u = t & 3;
            int nl = nloc0 - 1 + r;
            ushort4 o0 = make_ushort4(0,0,0,0), o1 = make_ushort4(0,0,0,0);
            if ((unsigned)nl < 4096u) {
                const float4* s = (const float4*)(x + ((size_t)(bb << 12) + nl) * 256 + c0 + u * 8);
                float4 f0 = s[0], f1 = s[1];
                o0 = make_ushort4(f2b(f0.x), f2b(f0.y), f2b(f0.z), f2b(f0.w));
                o1 = make_ushort4(f2b(f1.x), f2b(f1.y), f2b(f1.z), f2b(f1.w));
            }
            char* d = &slab[r * SLDW + u * 16];
            *(ushort4*)(d)     = o0;
            *(ushort4*)(d + 8) = o1;
        }
        {   // B: 1 thread/row, 3 taps x 64B from wcB (L2-resident)
            const unsigned short* wrow = wcB + (size_t)t * 768 + c0;
            #pragma unroll
            for (int p = 0; p < 3; ++p) {
                const uint4* s = (const uint4*)(wrow + p * 256);
                char* d = &Bs[p * 256 * SLDW + t * SLDW];
                *(uint4*)(d)      = s[0];
                *(uint4*)(d + 16) = s[1];
                *(uint4*)(d + 32) = s[2];
                *(uint4*)(d + 48) = s[3];
            }
        }
        __syncthreads();
        #pragma unroll
        for (int p = 0; p < 3; ++p) {
            bf16x8 bfr[4];
            #pragma unroll
            for (int ni = 0; ni < 4; ++ni)
                bfr[ni] = *(bf16x8*)&Bs[p * 256 * SLDW + (w * 64 + ni * 16 + row16) * SLDW + kg * 16];
            #pragma unroll
            for (int mi = 0; mi < 4; ++mi) {
                bf16x8 afr = *(bf16x8*)&slab[(mi * 16 + row16 + p) * SLDW + kg * 16];
                #pragma unroll
                for (int ni = 0; ni < 4; ++ni)
                    acc[mi][ni] = __builtin_amdgcn_mfma_f32_16x16x32_bf16(afr, bfr[ni], acc[mi][ni], 0, 0, 0);
            }
        }
    }
    #pragma unroll
    for (int mi = 0; mi < 4; ++mi)
        #pragma unroll
        for (int ni = 0; ni < 4; ++ni) {
            int coll = w * 64 + ni * 16 + row16;
            float bc = tcb[coll];
            #pragma unroll
            for (int q = 0; q < 4; ++q) {
                int rowl = mi * 16 + kg * 4 + q;
                size_t node = (size_t)(m0 + rowl);
                float v = acc[mi][ni][q] + bc + x[node * 256 + coll];   // exact fp32 residual
                v = v > 0.f ? v : 0.f;
                hAb[node * 256 + coll] = f2b(v);
            }
        }
}

// ---------------- full MFMA GEMM (layer 1) + fused s/d partials + S1 build (no fence) ----------------
__global__ __launch_bounds__(256) void k_gemm_layer(const unsigned short* __restrict__ hAb,
                                                    const unsigned short* __restrict__ WT,
                                                    const float* __restrict__ as, const float* __restrict__ ad,
                                                    unsigned short* __restrict__ hwB,
                                                    float* __restrict__ sPart, float* __restrict__ dPart,
                                                    const int* __restrict__ cnt, const int* __restrict__ csr,
                                                    int* __restrict__ flag1,
                                                    int* __restrict__ list1, const int* __restrict__ list2,
                                                    int* __restrict__ ct) {
    __shared__ char lds[128 * LDW + 64 * LDW];
    __shared__ float sRed[256], dRed[256];
    char* As = lds;
    char* Bs = lds + 128 * LDW;
    int t = threadIdx.x;
    if (blockIdx.x == 128) {   // S1 = dedup(buckets of S2); 4 blocks, no fence (round-14 lesson)
        int lane = t & 63;
        int n2 = ct[0];
        int total = n2 * CAP;
        for (int p = blockIdx.y * 256 + t; p < total; p += 1024) {
            int node = list2[p >> 6];
            int j = p & (CAP - 1);
            int src = 0; bool isNew = false;
            if (j < cnt[node]) {
                src = csr[node * CAP + j];
                isNew = (atomicExch(&flag1[src], 1) == 0);
            }
            wave_append(isNew, src, lane, &ct[1], list1);
        }
        return;
    }
    int m0 = blockIdx.x * 128, n0 = blockIdx.y * 64;
    int w = t >> 6, lane = t & 63;
    int wr = w >> 1, wc = w & 1;
    int row16 = lane & 15, kg = lane >> 4;
    int rA = t >> 1, hh = t & 1;
    f32x4 acc[4][2];
    #pragma unroll
    for (int mi = 0; mi < 4; ++mi)
        #pragma unroll
        for (int ni = 0; ni < 2; ++ni) acc[mi][ni] = (f32x4)(0.f);

    for (int kb = 0; kb < 256; kb += 32) {
        {
            const uint4* src = (const uint4*)(hAb + (size_t)(m0 + rA) * 256 + kb + hh * 16);
            uint4 v0 = src[0], v1 = src[1];
            *(uint4*)&As[rA * LDW + hh * 32] = v0;
            *(uint4*)&As[rA * LDW + hh * 32 + 16] = v1;
        }
        if (t < 128) {
            int rB = t >> 1;
            const uint4* src = (const uint4*)(WT + (size_t)(n0 + rB) * 256 + kb + hh * 16);
            uint4 v0 = src[0], v1 = src[1];
            *(uint4*)&Bs[rB * LDW + hh * 32] = v0;
            *(uint4*)&Bs[rB * LDW + hh * 32 + 16] = v1;
        }
        __syncthreads();
        bf16x8 bfr[2];
        #pragma unroll
        for (int ni = 0; ni < 2; ++ni)
            bfr[ni] = *(bf16x8*)&Bs[(wc * 32 + ni * 16 + row16) * LDW + kg * 16];
        #pragma unroll
        for (int mi = 0; mi < 4; ++mi) {
            bf16x8 afr = *(bf16x8*)&As[(wr * 64 + mi * 16 + row16) * LDW + kg * 16];
            acc[mi][0] = __builtin_amdgcn_mfma_f32_16x16x32_bf16(afr, bfr[0], acc[mi][0], 0, 0, 0);
            acc[mi][1] = __builtin_amdgcn_mfma_f32_16x16x32_bf16(afr, bfr[1], acc[mi][1], 0, 0, 0);
        }
        __syncthreads();
    }
    #pragma unroll
    for (int mi = 0; mi < 4; ++mi)
        #pragma unroll
        for (int ni = 0; ni < 2; ++ni) {
            int rowl = wr * 64 + mi * 16 + kg * 4;
            int coll = wc * 32 + ni * 16 + row16;
            size_t base = (size_t)(m0 + rowl) * 256 + n0 + coll;
            #pragma unroll
            for (int q = 0; q < 4; ++q) hwB[base + (size_t)q * 256] = f2b(acc[mi][ni][q]);
        }
    float asv0 = as[n0 + wc * 32 + row16];
    float asv1 = as[n0 + wc * 32 + 16 + row16];
    float adv0 = ad[n0 + wc * 32 + row16];
    float adv1 = ad[n0 + wc * 32 + 16 + row16];
    #pragma unroll
    for (int mi = 0; mi < 4; ++mi)
        #pragma unroll
        for (int q = 0; q < 4; ++q) {
            float ps = acc[mi][0][q] * asv0 + acc[mi][1][q] * asv1;
            float pd = acc[mi][0][q] * adv0 + acc[mi][1][q] * adv1;
            #pragma unroll
            for (int o = 1; o < 16; o <<= 1) { ps += __shfl_xor(ps, o); pd += __shfl_xor(pd, o); }
            if (row16 == 0) {
                int rowl = wr * 64 + mi * 16 + kg * 4 + q;
                sRed[rowl * 2 + wc] = ps;
                dRed[rowl * 2 + wc] = pd;
            }
        }
    __syncthreads();
    if (t < 128) {
        sPart[(size_t)blockIdx.y * NTOT + m0 + t] = sRed[t * 2] + sRed[t * 2 + 1];
        dPart[(size_t)blockIdx.y * NTOT + m0 + t] = dRed[t * 2] + dRed[t * 2 + 1];
    }
}

// ---------------- list-restricted MFMA GEMM (layers 2,3) ----------------
__global__ __launch_bounds__(256) void k_gemm_list(const unsigned short* __restrict__ hAb,
                                                   const unsigned short* __restrict__ WT,
                                                   const float* __restrict__ as, const float* __restrict__ ad,
                                                   unsigned short* __restrict__ hwB,
                                                   float* __restrict__ sPart, float* __restrict__ dPart,
                                                   const int* __restrict__ list, const int* __restrict__ cptr) {
    __shared__ char lds[128 * LDW + 64 * LDW];
    __shared__ float sRed[256], dRed[256];
    __shared__ int rows[128];
    char* As = lds;
    char* Bs = lds + 128 * LDW;
    int t = threadIdx.x;
    int n = *cptr;
    int m0 = blockIdx.x * 128;
    if (m0 >= n) return;
    int n0 = blockIdx.y * 64;
    if (t < 128) {
        int idx = m0 + t;
        rows[t] = list[idx < n ? idx : n - 1];
    }
    __syncthreads();
    int w = t >> 6, lane = t & 63;
    int wr = w >> 1, wc = w & 1;
    int row16 = lane & 15, kg = lane >> 4;
    int rA = t >> 1, hh = t & 1;
    f32x4 acc[4][2];
    #pragma unroll
    for (int mi = 0; mi < 4; ++mi)
        #pragma unroll
        for (int ni = 0; ni < 2; ++ni) acc[mi][ni] = (f32x4)(0.f);

    for (int kb = 0; kb < 256; kb += 32) {
        {
            const uint4* src = (const uint4*)(hAb + (size_t)rows[rA] * 256 + kb + hh * 16);
            uint4 v0 = src[0], v1 = src[1];
            *(uint4*)&As[rA * LDW + hh * 32] = v0;
            *(uint4*)&As[rA * LDW + hh * 32 + 16] = v1;
        }
        if (t < 128) {
            int rB = t >> 1;
            const uint4* src = (const uint4*)(WT + (size_t)(n0 + rB) * 256 + kb + hh * 16);
            uint4 v0 = src[0], v1 = src[1];
            *(uint4*)&Bs[rB * LDW + hh * 32] = v0;
            *(uint4*)&Bs[rB * LDW + hh * 32 + 16] = v1;
        }
        __syncthreads();
        bf16x8 bfr[2];
        #pragma unroll
        for (int ni = 0; ni < 2; ++ni)
            bfr[ni] = *(bf16x8*)&Bs[(wc * 32 + ni * 16 + row16) * LDW + kg * 16];
        #pragma unroll
        for (int mi = 0; mi < 4; ++mi) {
            bf16x8 afr = *(bf16x8*)&As[(wr * 64 + mi * 16 + row16) * LDW + kg * 16];
            acc[mi][0] = __builtin_amdgcn_mfma_f32_16x16x32_bf16(afr, bfr[0], acc[mi][0], 0, 0, 0);
            acc[mi][1] = __builtin_amdgcn_mfma_f32_16x16x32_bf16(afr, bfr[1], acc[mi][1], 0, 0, 0);
        }
        __syncthreads();
    }
    #pragma unroll
    for (int mi = 0; mi < 4; ++mi)
        #pragma unroll
        for (int ni = 0; ni < 2; ++ni) {
            int rowl = wr * 64 + mi * 16 + kg * 4;
            int coll = wc * 32 + ni * 16 + row16;
            #pragma unroll
            for (int q = 0; q < 4; ++q)
                hwB[(size_t)rows[rowl + q] * 256 + n0 + coll] = f2b(acc[mi][ni][q]);
        }
    float asv0 = as[n0 + wc * 32 + row16];
    float asv1 = as[n0 + wc * 32 + 16 + row16];
    float adv0 = ad[n0 + wc * 32 + row16];
    float adv1 = ad[n0 + wc * 32 + 16 + row16];
    #pragma unroll
    for (int mi = 0; mi < 4; ++mi)
        #pragma unroll
        for (int q = 0; q < 4; ++q) {
            float ps = acc[mi][0][q] * asv0 + acc[mi][1][q] * asv1;
            float pd = acc[mi][0][q] * adv0 + acc[mi][1][q] * adv1;
            #pragma unroll
            for (int o = 1; o < 16; o <<= 1) { ps += __shfl_xor(ps, o); pd += __shfl_xor(pd, o); }
            if (row16 == 0) {
                int rowl = wr * 64 + mi * 16 + kg * 4 + q;
                sRed[rowl * 2 + wc] = ps;
                dRed[rowl * 2 + wc] = pd;
            }
        }
    __syncthreads();
    if (t < 128) {
        int node = rows[t];
        sPart[(size_t)blockIdx.y * NTOT + node] = sRed[t * 2] + sRed[t * 2 + 1];
        dPart[(size_t)blockIdx.y * NTOT + node] = dRed[t * 2] + dRed[t * 2 + 1];
    }
}

// list-restricted edge softmax + aggregate (grid-stride over list)
__global__ __launch_bounds__(256) void k_agg_list(const unsigned short* __restrict__ hwB,
                                                  const float* __restrict__ sPart, const float* __restrict__ dPart,
                                                  const int* __restrict__ cnt, const int* __restrict__ csr,
                                                  const float* __restrict__ bias,
                                                  unsigned short* __restrict__ hout,
                                                  const int* __restrict__ list, const int* __restrict__ cptr) {
    int tid = threadIdx.x;
    int wave = tid >> 6, lane = tid & 63;
    int n = *cptr;
    const ushort4* hw4 = (const ushort4*)hwB;
    for (int idx = blockIdx.x * 4 + wave; idx < n; idx += gridDim.x * 4) {
        int node = list[idx];
        int deg = cnt[node];
        const int* bucket = csr + node * CAP;
        float di = dPart[node] + dPart[NTOT + node] + dPart[2 * NTOT + node] + dPart[3 * NTOT + node];
        float denom = 0.f;
        float a0 = 0.f, a1 = 0.f, a2 = 0.f, a3 = 0.f;
        for (int cb = 0; cb < deg; cb += 64) {
            int j = cb + lane;
            int sj = 0;
            float myw = 0.f;
            if (j < deg) {
                sj = bucket[j];
                float sv = sPart[sj] + sPart[NTOT + sj] + sPart[2 * NTOT + sj] + sPart[3 * NTOT + sj];
                float e = sv + di;
                e = e > 0.f ? e : SLOPE * e;
                myw = __expf(e);
            }
            float csum = myw;
            #pragma unroll
            for (int o = 1; o < 64; o <<= 1) csum += __shfl_xor(csum, o);
            denom += csum;
            int c = deg - cb; if (c > 64) c = 64;
            int q = 0;
            for (; q + 8 <= c; q += 8) {
                int si[8]; float wi[8]; ushort4 vv[8];
                #pragma unroll
                for (int u = 0; u < 8; ++u) {
                    si[u] = __builtin_amdgcn_readlane(sj, q + u);
                    wi[u] = rlanef(myw, q + u);
                }
                #pragma unroll
                for (int u = 0; u < 8; ++u) vv[u] = hw4[(size_t)si[u] * 64 + lane];
                #pragma unroll
                for (int u = 0; u < 8; ++u) {
                    a0 = fmaf(wi[u], b2f(vv[u].x), a0);
                    a1 = fmaf(wi[u], b2f(vv[u].y), a1);
                    a2 = fmaf(wi[u], b2f(vv[u].z), a2);
                    a3 = fmaf(wi[u], b2f(vv[u].w), a3);
                }
            }
            if (q < c) {
                int rem = c - q;
                int si[8]; float wi[8]; ushort4 vv[8];
                #pragma unroll
                for (int u = 0; u < 8; ++u) {
                    int qq = q + (u < rem ? u : 0);
                    si[u] = __builtin_amdgcn_readlane(sj, qq);
                    wi[u] = (u < rem) ? rlanef(myw, qq) : 0.f;
                }
                #pragma unroll
                for (int u = 0; u < 8; ++u) vv[u] = hw4[(size_t)si[u] * 64 + lane];
                #pragma unroll
                for (int u = 0; u < 8; ++u) {
                    a0 = fmaf(wi[u], b2f(vv[u].x), a0);
                    a1 = fmaf(wi[u], b2f(vv[u].y), a1);
                    a2 = fmaf(wi[u], b2f(vv[u].z), a2);
                    a3 = fmaf(wi[u], b2f(vv[u].w), a3);
                }
            }
        }
        float inv = 1.f / denom;
        float4 bb = ((const float4*)bias)[lane];
        ushort4 o;
        float o0 = a0 * inv + bb.x; o.x = f2b(o0 > 0.f ? o0 : 0.f);
        float o1 = a1 * inv + bb.y; o.y = f2b(o1 > 0.f ? o1 : 0.f);
        float o2 = a2 * inv + bb.z; o.z = f2b(o2 > 0.f ? o2 : 0.f);
        float o3 = a3 * inv + bb.w; o.w = f2b(o3 > 0.f ? o3 : 0.f);
        ((ushort4*)hout)[(size_t)node * 64 + lane] = o;
    }
}

// ---------------- fused layer-3 agg (8 dst nodes) + final conv + LayerNorm + relu ----------------
__global__ __launch_bounds__(256) void k_aggfinal(const unsigned short* __restrict__ hwB,
                                                  const float* __restrict__ sPart, const float* __restrict__ dPart,
                                                  const int* __restrict__ cnt, const int* __restrict__ csr,
                                                  const float* __restrict__ bias,
                                                  const float* __restrict__ wT, const float* __restrict__ tcb,
                                                  const float* __restrict__ g, const float* __restrict__ bln,
                                                  float* __restrict__ out) {
    __shared__ float r01[2][HDIM];
    __shared__ float red[16];
    int b = blockIdx.x, t = threadIdx.x;
    int w = t >> 6, lane = t & 63;
    if (w < 2) {
        int node = b * NSEQ + w;
        int deg = cnt[node];
        const int* bucket = csr + node * CAP;
        float di = dPart[node] + dPart[NTOT + node] + dPart[2 * NTOT + node] + dPart[3 * NTOT + node];
        const ushort4* hw4 = (const ushort4*)hwB;
        float denom = 0.f;
        float a0 = 0.f, a1 = 0.f, a2 = 0.f, a3 = 0.f;
        for (int cb = 0; cb < deg; cb += 64) {
            int j = cb + lane;
            int sj = 0;
            float myw = 0.f;
            if (j < deg) {
                sj = bucket[j];
                float sv = sPart[sj] + sPart[NTOT + sj] + sPart[2 * NTOT + sj] + sPart[3 * NTOT + sj];
                float e = sv + di;
                e = e > 0.f ? e : SLOPE * e;
                myw = __expf(e);
            }
            float csum = myw;
            #pragma unroll
            for (int o = 1; o < 64; o <<= 1) csum += __shfl_xor(csum, o);
            denom += csum;
            int c = deg - cb; if (c > 64) c = 64;
            for (int q = 0; q < c; ++q) {
                int sq = __builtin_amdgcn_readlane(sj, q);
                float wq = rlanef(myw, q);
                ushort4 v = hw4[(size_t)sq * 64 + lane];
                a0 = fmaf(wq, b2f(v.x), a0); a1 = fmaf(wq, b2f(v.y), a1);
                a2 = fmaf(wq, b2f(v.z), a2); a3 = fmaf(wq, b2f(v.w), a3);
            }
        }
        float inv = 1.f / denom;
        float4 bb = ((const float4*)bias)[lane];
        float o0 = a0 * inv + bb.x;
        float o1 = a1 * inv + bb.y;
        float o2 = a2 * inv + bb.z;
        float o3 = a3 * inv + bb.w;
        r01[w][lane * 4 + 0] = o0 > 0.f ? o0 : 0.f;
        r01[w][lane * 4 + 1] = o1 > 0.f ? o1 : 0.f;
        r01[w][lane * 4 + 2] = o2 > 0.f ? o2 : 0.f;
        r01[w][lane * 4 + 3] = o3 > 0.f ? o3 : 0.f;
    }
    __syncthreads();
    int c = t;
    float a = tcb[c];
    for (int f = 0; f < FDIM; ++f) {
        a = fmaf(wT[(1 * FDIM + f) * HDIM + c], r01[0][f], a);
        a = fmaf(wT[(2 * FDIM + f) * HDIM + c], r01[1][f], a);
    }
    float ss = a, sq = a * a;
    #pragma unroll
    for (int o = 1; o < 64; o <<= 1) { ss += __shfl_xor(ss, o); sq += __shfl_xor(sq, o); }
    if (lane == 0) { red[w] = ss; red[8 + w] = sq; }
    __syncthreads();
    float tot = 0.f, totq = 0.f;
    #pragma unroll
    for (int u = 0; u < 4; ++u) { tot += red[u]; totq += red[8 + u]; }
    float mu = tot * (1.f / HDIM);
    float var = totq * (1.f / HDIM) - mu * mu;
    float v = (a - mu) * rsqrtf(var + LN_EPS) * g[c] + bln[c];
    out[b * HDIM + c] = v > 0.f ? v : 0.f;
}

extern "C" void kernel_launch(void* const* d_in, const int* in_sizes, int n_in,
                              void* d_out, int out_size, void* d_ws, size_t ws_size,
                              hipStream_t stream) {
    const float* x     = (const float*)d_in[0];
    const int*   ei    = (const int*)d_in[1];
    const float* tcw   = (const float*)d_in[2];
    const float* tcb   = (const float*)d_in[3];
    const float* gatW  = (const float*)d_in[4];
    const float* gatas = (const float*)d_in[5];
    const float* gatad = (const float*)d_in[6];
    const float* gatb  = (const float*)d_in[7];
    const float* lng   = (const float*)d_in[8];
    const float* lnb   = (const float*)d_in[9];
    float* out = (float*)d_out;

    char* ws = (char*)d_ws;
    unsigned short* hAb = (unsigned short*)(ws + OFF_HA);
    unsigned short* hwB = (unsigned short*)(ws + OFF_HW);
    unsigned short* wcB = (unsigned short*)(ws + OFF_WC);
    unsigned short* WTb = (unsigned short*)(ws + OFF_WL);
    float* sPart = (float*)(ws + OFF_SP);
    float* dPart = (float*)(ws + OFF_DP);
    int*   cnt  = (int*)(ws + OFF_CNT);
    int*   csr  = (int*)(ws + OFF_CSR);
    float* wT   = (float*)(ws + OFF_WT);
    int*   flag1 = (int*)(ws + OFF_F1);
    int*   flag2 = (int*)(ws + OFF_F2);
    int*   list1 = (int*)(ws + OFF_L1);
    int*   list2 = (int*)(ws + OFF_L2);
    int*   ct    = (int*)(ws + OFF_CT);

    k_pre<<<1841, 256, 0, stream>>>(tcw, gatW, wcB, WTb, wT, cnt, flag1, flag2, ct);
    // conv (BM=64, full-N) + scatter + S2 build
    k_conv<<<dim3(64 + 272, 4), 256, 0, stream>>>(x, wcB, tcb, hAb, ei, cnt, csr,
                                                  flag2, list2, ct);

    // layer 1: full GEMM + S1 build, then agg over S1
    k_gemm_layer<<<dim3(129, 4), 256, 0, stream>>>(
        hAb, WTb, gatas, gatad, hwB, sPart, dPart,
        cnt, csr, flag1, list1, list2, ct);
    k_agg_list<<<1024, 256, 0, stream>>>(hwB, sPart, dPart, cnt, csr, gatb, hAb, list1, ct + 1);

    // layer 2: GEMM over S1 rows, agg restricted to S2
    k_gemm_list<<<dim3(128, 4), 256, 0, stream>>>(
        hAb, WTb + 65536, gatas + HDIM, gatad + HDIM, hwB, sPart, dPart, list1, ct + 1);
    k_agg_list<<<128, 256, 0, stream>>>(hwB, sPart, dPart, cnt, csr, gatb + HDIM, hAb, list2, ct);

    // layer 3: GEMM over S2 rows, then fused 8-node agg + final conv + LN
    k_gemm_list<<<dim3(4, 4), 256, 0, stream>>>(
        hAb, WTb + 131072, gatas + 2 * HDIM, gatad + 2 * HDIM, hwB, sPart, dPart, list2, ct);
    k_aggfinal<<<BBATCH, 256, 0, stream>>>(hwB, sPart, dPart, cnt, csr, gatb + 2 * HDIM,
                                           wT, tcb, lng, lnb, out);
}

// Round 18
// 117.498 us; speedup vs baseline: 1.1408x; 1.1408x over previous
//
#include <hip/hip_runtime.h>
#include <hip/hip_bf16.h>
#include <math.h>

#define NTOT 16384
#define HDIM 256
#define BBATCH 4
#define NSEQ 4096
#define FDIM 256
#define NE 262144
#define NEE (NE + NTOT)
#define NLAYER 3
#define LN_EPS 1e-5f
#define SLOPE 0.2f
#define CAP 64   // bucket capacity; deg ~ Poisson(17), overflow prob ~1e-13

typedef __attribute__((ext_vector_type(8))) short bf16x8;
typedef __attribute__((ext_vector_type(4))) float f32x4;

#define LDW 80    // gemm LDS row stride bytes
#define SLDW 72   // conv slab row stride bytes (18-word stride -> 2-way alias max, free)

// ---- workspace layout (bytes) ----
#define OFF_HA   0u          // ushort[NTOT*256]   8388608
#define OFF_HW   8388608u    // ushort[NTOT*256]   8388608
#define OFF_WC   16777216u   // ushort[256*768]    393216
#define OFF_WL   17170432u   // ushort[3*256*256]  393216
#define OFF_SP   17563648u   // float[4*NTOT]      262144
#define OFF_DP   17825792u   // float[4*NTOT]      262144
#define OFF_CNT  18087936u   // int[NTOT]          65536
#define OFF_CSR  18153472u   // int[NTOT*CAP]      4194304
#define OFF_WT   22347776u   // float[3*256*256]   786432
#define OFF_F1   23134208u   // int[NTOT] flag level-1
#define OFF_F2   23199744u   // int[NTOT] flag level-2
#define OFF_L1   23265280u   // int[NTOT] list S1
#define OFF_L2   23330816u   // int[NTOT] list S2
#define OFF_CT   23396352u   // int[2]: ct[0]=|S2|, ct[1]=|S1|

static __device__ __forceinline__ unsigned short f2b(float f) {
    __hip_bfloat16 h = __float2bfloat16(f);
    return __builtin_bit_cast(unsigned short, h);
}
static __device__ __forceinline__ float b2f(unsigned short u) {
    __hip_bfloat16 h = __builtin_bit_cast(__hip_bfloat16, u);
    return __bfloat162float(h);
}
static __device__ __forceinline__ float rlanef(float v, int l) {
    return __builtin_bit_cast(float, __builtin_amdgcn_readlane(__builtin_bit_cast(int, v), l));
}

// wave-aggregated list append: one atomicAdd per wave, plain stores.
static __device__ __forceinline__ void wave_append(bool isNew, int src, int lane,
                                                   int* ctp, int* list) {
    unsigned long long mask = __ballot(isNew);
    int base = 0;
    if (lane == 0 && mask) base = atomicAdd(ctp, (int)__popcll(mask));
    base = __shfl(base, 0);
    if (isNew) {
        int off = (int)__popcll(mask & ((1ull << lane) - 1ull));
        list[base + off] = src;
    }
}

// ---- pre-pass: weight prep + zero cnt/flags/ctrs ----
__global__ __launch_bounds__(256) void k_pre(const float* __restrict__ tcw, const float* __restrict__ gatW,
                                             unsigned short* __restrict__ wcB, unsigned short* __restrict__ WTb,
                                             float* __restrict__ wT, int* __restrict__ cnt,
                                             int* __restrict__ flag1, int* __restrict__ flag2,
                                             int* __restrict__ ct) {
    int b = blockIdx.x, t = threadIdx.x;
    if (b < 256) {
        const float* s = tcw + b * 768 + t * 3;
        wcB[b * 768 + 0 + t]   = f2b(s[0]);
        wcB[b * 768 + 256 + t] = f2b(s[1]);
        wcB[b * 768 + 512 + t] = f2b(s[2]);
    } else if (b < 1024) {
        int ln = b - 256; int n = ln & 255; int l = ln >> 8;
        WTb[(size_t)l * 65536 + n * 256 + t] = f2b(gatW[(size_t)l * 65536 + t * 256 + n]);
    } else if (b < 1792) {
        int fk = b - 1024; int f = fk / 3, k = fk - 3 * f;
        wT[(k * FDIM + f) * HDIM + t] = tcw[t * 768 + fk];
    } else if (b < 1808) {
        int i = ((b - 1792) * 256 + t) * 4;
        *(int4*)(cnt + i) = make_int4(0, 0, 0, 0);
    } else if (b < 1824) {
        int i = ((b - 1808) * 256 + t) * 4;
        *(int4*)(flag1 + i) = make_int4(0, 0, 0, 0);
    } else if (b < 1840) {
        int i = ((b - 1824) * 256 + t) * 4;
        *(int4*)(flag2 + i) = make_int4(0, 0, 0, 0);
    } else {
        if (t < 2) ct[t] = 0;
    }
}

// ---------------- conv GEMM (round-15 shape: BM=128 x BN=64, 130-row halo slab,
// 24.7KB LDS -> 3-4 blocks/CU; round-17 lesson: BM=64 x full-N at 60KB LDS dropped
// occupancy to 2 blocks/CU and regressed 16us) + bucket SCATTER + S2 build ----------------
__global__ __launch_bounds__(256) void k_conv(const float* __restrict__ x,
                                              const unsigned short* __restrict__ wcB,
                                              const float* __restrict__ tcb,
                                              unsigned short* __restrict__ hAb,
                                              const int* __restrict__ ei, int* __restrict__ cnt,
                                              int* __restrict__ csr,
                                              int* __restrict__ flag2, int* __restrict__ list2,
                                              int* __restrict__ ct) {
    __shared__ char slab[130 * SLDW];      // 9360 B
    __shared__ char Bs[3 * 64 * LDW];      // 15360 B
    int t = threadIdx.x;
    if (blockIdx.x >= 128) {   // bucket scatter + S2 detection
        int cid = (blockIdx.x - 128) * 4 + blockIdx.y;   // 0..1087
        int e = cid * 256 + t;
        int src, dst;
        if (e < NE) { src = ei[e]; dst = ei[NE + e]; } else { src = dst = e - NE; }
        int slot = atomicAdd(&cnt[dst], 1);
        if (slot < CAP) csr[dst * CAP + slot] = src;
        bool isNew = false;
        if ((dst & 4095) < 2) isNew = (atomicExch(&flag2[src], 1) == 0);
        wave_append(isNew, src, t & 63, &ct[0], list2);
        return;
    }
    int m0 = blockIdx.x * 128, n0 = blockIdx.y * 64;
    int bb = m0 >> 12;
    int nloc0 = m0 & 4095;
    int w = t >> 6, lane = t & 63;
    int wr = w >> 1, wc = w & 1;
    int row16 = lane & 15, kg = lane >> 4;
    int rA = t >> 1, hh = t & 1;
    f32x4 acc[4][2];
    #pragma unroll
    for (int mi = 0; mi < 4; ++mi)
        #pragma unroll
        for (int ni = 0; ni < 2; ++ni) acc[mi][ni] = (f32x4)(0.f);

    for (int kb = 0; kb < 8; ++kb) {
        int c0 = kb * 32;
        __syncthreads();   // previous step's MFMA reads complete before overwrite
        {   // slab rows 0..127: 2 threads/row, 16 fp32 (64B) -> 32B bf16 each
            int nl = nloc0 - 1 + rA;
            ushort4 o0 = make_ushort4(0,0,0,0), o1 = make_ushort4(0,0,0,0),
                    o2 = make_ushort4(0,0,0,0), o3 = make_ushort4(0,0,0,0);
            if ((unsigned)nl < 4096u) {
                const float4* s = (const float4*)(x + ((size_t)(bb << 12) + nl) * 256 + c0 + hh * 16);
                float4 f0 = s[0], f1 = s[1], f2 = s[2], f3 = s[3];
                o0 = make_ushort4(f2b(f0.x), f2b(f0.y), f2b(f0.z), f2b(f0.w));
                o1 = make_ushort4(f2b(f1.x), f2b(f1.y), f2b(f1.z), f2b(f1.w));
                o2 = make_ushort4(f2b(f2.x), f2b(f2.y), f2b(f2.z), f2b(f2.w));
                o3 = make_ushort4(f2b(f3.x), f2b(f3.y), f2b(f3.z), f2b(f3.w));
            }
            char* dstp = &slab[rA * SLDW + hh * 32];
            *(ushort4*)(dstp)      = o0;
            *(ushort4*)(dstp + 8)  = o1;
            *(ushort4*)(dstp + 16) = o2;
            *(ushort4*)(dstp + 24) = o3;
        }
        if (t < 16) {  // slab rows 128,129: 8 threads/row, 8 fp32 (32B) -> 16B bf16
            int r = 128 + (t >> 3), u = t & 7;
            int nl = nloc0 - 1 + r;
            ushort4 o = make_ushort4(0,0,0,0);
            if ((unsigned)nl < 4096u) {
                const float4* s = (const float4*)(x + ((size_t)(bb << 12) + nl) * 256 + c0 + u * 4);
                float4 f = s[0];
                o = make_ushort4(f2b(f.x), f2b(f.y), f2b(f.z), f2b(f.w));
            }
            *(ushort4*)&slab[r * SLDW + u * 8] = o;
        }
        {   // B: 3 taps x 64 rows x 64B
            int rB = t >> 2, u = t & 3;
            const unsigned short* wrow = wcB + (size_t)(n0 + rB) * 768 + c0 + u * 8;
            #pragma unroll
            for (int p = 0; p < 3; ++p)
                *(uint4*)&Bs[p * 64 * LDW + rB * LDW + u * 16] = *(const uint4*)(wrow + p * 256);
        }
        __syncthreads();
        #pragma unroll
        for (int p = 0; p < 3; ++p) {
            bf16x8 bfr[2];
            #pragma unroll
            for (int ni = 0; ni < 2; ++ni)
                bfr[ni] = *(bf16x8*)&Bs[p * 64 * LDW + (wc * 32 + ni * 16 + row16) * LDW + kg * 16];
            #pragma unroll
            for (int mi = 0; mi < 4; ++mi) {
                bf16x8 afr = *(bf16x8*)&slab[(wr * 64 + mi * 16 + row16 + p) * SLDW + kg * 16];
                acc[mi][0] = __builtin_amdgcn_mfma_f32_16x16x32_bf16(afr, bfr[0], acc[mi][0], 0, 0, 0);
                acc[mi][1] = __builtin_amdgcn_mfma_f32_16x16x32_bf16(afr, bfr[1], acc[mi][1], 0, 0, 0);
            }
        }
    }
    #pragma unroll
    for (int mi = 0; mi < 4; ++mi)
        #pragma unroll
        for (int ni = 0; ni < 2; ++ni) {
            int rowl = wr * 64 + mi * 16 + kg * 4;
            int coll = wc * 32 + ni * 16 + row16;
            int n = n0 + coll;
            float bc = tcb[n];
            #pragma unroll
            for (int q = 0; q < 4; ++q) {
                size_t node = (size_t)(m0 + rowl + q);
                float v = acc[mi][ni][q] + bc + x[node * 256 + n];   // exact fp32 residual
                v = v > 0.f ? v : 0.f;
                hAb[node * 256 + n] = f2b(v);
            }
        }
}

// ---------------- full MFMA GEMM (layer 1) + fused s/d partials + S1 build (no fence) ----------------
__global__ __launch_bounds__(256) void k_gemm_layer(const unsigned short* __restrict__ hAb,
                                                    const unsigned short* __restrict__ WT,
                                                    const float* __restrict__ as, const float* __restrict__ ad,
                                                    unsigned short* __restrict__ hwB,
                                                    float* __restrict__ sPart, float* __restrict__ dPart,
                                                    const int* __restrict__ cnt, const int* __restrict__ csr,
                                                    int* __restrict__ flag1,
                                                    int* __restrict__ list1, const int* __restrict__ list2,
                                                    int* __restrict__ ct) {
    __shared__ char lds[128 * LDW + 64 * LDW];
    __shared__ float sRed[256], dRed[256];
    char* As = lds;
    char* Bs = lds + 128 * LDW;
    int t = threadIdx.x;
    if (blockIdx.x == 128) {   // S1 = dedup(buckets of S2); 4 blocks, no fence (round-14 lesson)
        int lane = t & 63;
        int n2 = ct[0];
        int total = n2 * CAP;
        for (int p = blockIdx.y * 256 + t; p < total; p += 1024) {
            int node = list2[p >> 6];
            int j = p & (CAP - 1);
            int src = 0; bool isNew = false;
            if (j < cnt[node]) {
                src = csr[node * CAP + j];
                isNew = (atomicExch(&flag1[src], 1) == 0);
            }
            wave_append(isNew, src, lane, &ct[1], list1);
        }
        return;
    }
    int m0 = blockIdx.x * 128, n0 = blockIdx.y * 64;
    int w = t >> 6, lane = t & 63;
    int wr = w >> 1, wc = w & 1;
    int row16 = lane & 15, kg = lane >> 4;
    int rA = t >> 1, hh = t & 1;
    f32x4 acc[4][2];
    #pragma unroll
    for (int mi = 0; mi < 4; ++mi)
        #pragma unroll
        for (int ni = 0; ni < 2; ++ni) acc[mi][ni] = (f32x4)(0.f);

    for (int kb = 0; kb < 256; kb += 32) {
        {
            const uint4* src = (const uint4*)(hAb + (size_t)(m0 + rA) * 256 + kb + hh * 16);
            uint4 v0 = src[0], v1 = src[1];
            *(uint4*)&As[rA * LDW + hh * 32] = v0;
            *(uint4*)&As[rA * LDW + hh * 32 + 16] = v1;
        }
        if (t < 128) {
            int rB = t >> 1;
            const uint4* src = (const uint4*)(WT + (size_t)(n0 + rB) * 256 + kb + hh * 16);
            uint4 v0 = src[0], v1 = src[1];
            *(uint4*)&Bs[rB * LDW + hh * 32] = v0;
            *(uint4*)&Bs[rB * LDW + hh * 32 + 16] = v1;
        }
        __syncthreads();
        bf16x8 bfr[2];
        #pragma unroll
        for (int ni = 0; ni < 2; ++ni)
            bfr[ni] = *(bf16x8*)&Bs[(wc * 32 + ni * 16 + row16) * LDW + kg * 16];
        #pragma unroll
        for (int mi = 0; mi < 4; ++mi) {
            bf16x8 afr = *(bf16x8*)&As[(wr * 64 + mi * 16 + row16) * LDW + kg * 16];
            acc[mi][0] = __builtin_amdgcn_mfma_f32_16x16x32_bf16(afr, bfr[0], acc[mi][0], 0, 0, 0);
            acc[mi][1] = __builtin_amdgcn_mfma_f32_16x16x32_bf16(afr, bfr[1], acc[mi][1], 0, 0, 0);
        }
        __syncthreads();
    }
    #pragma unroll
    for (int mi = 0; mi < 4; ++mi)
        #pragma unroll
        for (int ni = 0; ni < 2; ++ni) {
            int rowl = wr * 64 + mi * 16 + kg * 4;
            int coll = wc * 32 + ni * 16 + row16;
            size_t base = (size_t)(m0 + rowl) * 256 + n0 + coll;
            #pragma unroll
            for (int q = 0; q < 4; ++q) hwB[base + (size_t)q * 256] = f2b(acc[mi][ni][q]);
        }
    float asv0 = as[n0 + wc * 32 + row16];
    float asv1 = as[n0 + wc * 32 + 16 + row16];
    float adv0 = ad[n0 + wc * 32 + row16];
    float adv1 = ad[n0 + wc * 32 + 16 + row16];
    #pragma unroll
    for (int mi = 0; mi < 4; ++mi)
        #pragma unroll
        for (int q = 0; q < 4; ++q) {
            float ps = acc[mi][0][q] * asv0 + acc[mi][1][q] * asv1;
            float pd = acc[mi][0][q] * adv0 + acc[mi][1][q] * adv1;
            #pragma unroll
            for (int o = 1; o < 16; o <<= 1) { ps += __shfl_xor(ps, o); pd += __shfl_xor(pd, o); }
            if (row16 == 0) {
                int rowl = wr * 64 + mi * 16 + kg * 4 + q;
                sRed[rowl * 2 + wc] = ps;
                dRed[rowl * 2 + wc] = pd;
            }
        }
    __syncthreads();
    if (t < 128) {
        sPart[(size_t)blockIdx.y * NTOT + m0 + t] = sRed[t * 2] + sRed[t * 2 + 1];
        dPart[(size_t)blockIdx.y * NTOT + m0 + t] = dRed[t * 2] + dRed[t * 2 + 1];
    }
}

// ---------------- list-restricted MFMA GEMM (layers 2,3) ----------------
__global__ __launch_bounds__(256) void k_gemm_list(const unsigned short* __restrict__ hAb,
                                                   const unsigned short* __restrict__ WT,
                                                   const float* __restrict__ as, const float* __restrict__ ad,
                                                   unsigned short* __restrict__ hwB,
                                                   float* __restrict__ sPart, float* __restrict__ dPart,
                                                   const int* __restrict__ list, const int* __restrict__ cptr) {
    __shared__ char lds[128 * LDW + 64 * LDW];
    __shared__ float sRed[256], dRed[256];
    __shared__ int rows[128];
    char* As = lds;
    char* Bs = lds + 128 * LDW;
    int t = threadIdx.x;
    int n = *cptr;
    int m0 = blockIdx.x * 128;
    if (m0 >= n) return;
    int n0 = blockIdx.y * 64;
    if (t < 128) {
        int idx = m0 + t;
        rows[t] = list[idx < n ? idx : n - 1];
    }
    __syncthreads();
    int w = t >> 6, lane = t & 63;
    int wr = w >> 1, wc = w & 1;
    int row16 = lane & 15, kg = lane >> 4;
    int rA = t >> 1, hh = t & 1;
    f32x4 acc[4][2];
    #pragma unroll
    for (int mi = 0; mi < 4; ++mi)
        #pragma unroll
        for (int ni = 0; ni < 2; ++ni) acc[mi][ni] = (f32x4)(0.f);

    for (int kb = 0; kb < 256; kb += 32) {
        {
            const uint4* src = (const uint4*)(hAb + (size_t)rows[rA] * 256 + kb + hh * 16);
            uint4 v0 = src[0], v1 = src[1];
            *(uint4*)&As[rA * LDW + hh * 32] = v0;
            *(uint4*)&As[rA * LDW + hh * 32 + 16] = v1;
        }
        if (t < 128) {
            int rB = t >> 1;
            const uint4* src = (const uint4*)(WT + (size_t)(n0 + rB) * 256 + kb + hh * 16);
            uint4 v0 = src[0], v1 = src[1];
            *(uint4*)&Bs[rB * LDW + hh * 32] = v0;
            *(uint4*)&Bs[rB * LDW + hh * 32 + 16] = v1;
        }
        __syncthreads();
        bf16x8 bfr[2];
        #pragma unroll
        for (int ni = 0; ni < 2; ++ni)
            bfr[ni] = *(bf16x8*)&Bs[(wc * 32 + ni * 16 + row16) * LDW + kg * 16];
        #pragma unroll
        for (int mi = 0; mi < 4; ++mi) {
            bf16x8 afr = *(bf16x8*)&As[(wr * 64 + mi * 16 + row16) * LDW + kg * 16];
            acc[mi][0] = __builtin_amdgcn_mfma_f32_16x16x32_bf16(afr, bfr[0], acc[mi][0], 0, 0, 0);
            acc[mi][1] = __builtin_amdgcn_mfma_f32_16x16x32_bf16(afr, bfr[1], acc[mi][1], 0, 0, 0);
        }
        __syncthreads();
    }
    #pragma unroll
    for (int mi = 0; mi < 4; ++mi)
        #pragma unroll
        for (int ni = 0; ni < 2; ++ni) {
            int rowl = wr * 64 + mi * 16 + kg * 4;
            int coll = wc * 32 + ni * 16 + row16;
            #pragma unroll
            for (int q = 0; q < 4; ++q)
                hwB[(size_t)rows[rowl + q] * 256 + n0 + coll] = f2b(acc[mi][ni][q]);
        }
    float asv0 = as[n0 + wc * 32 + row16];
    float asv1 = as[n0 + wc * 32 + 16 + row16];
    float adv0 = ad[n0 + wc * 32 + row16];
    float adv1 = ad[n0 + wc * 32 + 16 + row16];
    #pragma unroll
    for (int mi = 0; mi < 4; ++mi)
        #pragma unroll
        for (int q = 0; q < 4; ++q) {
            float ps = acc[mi][0][q] * asv0 + acc[mi][1][q] * asv1;
            float pd = acc[mi][0][q] * adv0 + acc[mi][1][q] * adv1;
            #pragma unroll
            for (int o = 1; o < 16; o <<= 1) { ps += __shfl_xor(ps, o); pd += __shfl_xor(pd, o); }
            if (row16 == 0) {
                int rowl = wr * 64 + mi * 16 + kg * 4 + q;
                sRed[rowl * 2 + wc] = ps;
                dRed[rowl * 2 + wc] = pd;
            }
        }
    __syncthreads();
    if (t < 128) {
        int node = rows[t];
        sPart[(size_t)blockIdx.y * NTOT + node] = sRed[t * 2] + sRed[t * 2 + 1];
        dPart[(size_t)blockIdx.y * NTOT + node] = dRed[t * 2] + dRed[t * 2 + 1];
    }
}

// list-restricted edge softmax + aggregate (grid-stride over list)
__global__ __launch_bounds__(256) void k_agg_list(const unsigned short* __restrict__ hwB,
                                                  const float* __restrict__ sPart, const float* __restrict__ dPart,
                                                  const int* __restrict__ cnt, const int* __restrict__ csr,
                                                  const float* __restrict__ bias,
                                                  unsigned short* __restrict__ hout,
                                                  const int* __restrict__ list, const int* __restrict__ cptr) {
    int tid = threadIdx.x;
    int wave = tid >> 6, lane = tid & 63;
    int n = *cptr;
    const ushort4* hw4 = (const ushort4*)hwB;
    for (int idx = blockIdx.x * 4 + wave; idx < n; idx += gridDim.x * 4) {
        int node = list[idx];
        int deg = cnt[node];
        const int* bucket = csr + node * CAP;
        float di = dPart[node] + dPart[NTOT + node] + dPart[2 * NTOT + node] + dPart[3 * NTOT + node];
        float denom = 0.f;
        float a0 = 0.f, a1 = 0.f, a2 = 0.f, a3 = 0.f;
        for (int cb = 0; cb < deg; cb += 64) {
            int j = cb + lane;
            int sj = 0;
            float myw = 0.f;
            if (j < deg) {
                sj = bucket[j];
                float sv = sPart[sj] + sPart[NTOT + sj] + sPart[2 * NTOT + sj] + sPart[3 * NTOT + sj];
                float e = sv + di;
                e = e > 0.f ? e : SLOPE * e;
                myw = __expf(e);
            }
            float csum = myw;
            #pragma unroll
            for (int o = 1; o < 64; o <<= 1) csum += __shfl_xor(csum, o);
            denom += csum;
            int c = deg - cb; if (c > 64) c = 64;
            int q = 0;
            for (; q + 8 <= c; q += 8) {
                int si[8]; float wi[8]; ushort4 vv[8];
                #pragma unroll
                for (int u = 0; u < 8; ++u) {
                    si[u] = __builtin_amdgcn_readlane(sj, q + u);
                    wi[u] = rlanef(myw, q + u);
                }
                #pragma unroll
                for (int u = 0; u < 8; ++u) vv[u] = hw4[(size_t)si[u] * 64 + lane];
                #pragma unroll
                for (int u = 0; u < 8; ++u) {
                    a0 = fmaf(wi[u], b2f(vv[u].x), a0);
                    a1 = fmaf(wi[u], b2f(vv[u].y), a1);
                    a2 = fmaf(wi[u], b2f(vv[u].z), a2);
                    a3 = fmaf(wi[u], b2f(vv[u].w), a3);
                }
            }
            if (q < c) {
                int rem = c - q;
                int si[8]; float wi[8]; ushort4 vv[8];
                #pragma unroll
                for (int u = 0; u < 8; ++u) {
                    int qq = q + (u < rem ? u : 0);
                    si[u] = __builtin_amdgcn_readlane(sj, qq);
                    wi[u] = (u < rem) ? rlanef(myw, qq) : 0.f;
                }
                #pragma unroll
                for (int u = 0; u < 8; ++u) vv[u] = hw4[(size_t)si[u] * 64 + lane];
                #pragma unroll
                for (int u = 0; u < 8; ++u) {
                    a0 = fmaf(wi[u], b2f(vv[u].x), a0);
                    a1 = fmaf(wi[u], b2f(vv[u].y), a1);
                    a2 = fmaf(wi[u], b2f(vv[u].z), a2);
                    a3 = fmaf(wi[u], b2f(vv[u].w), a3);
                }
            }
        }
        float inv = 1.f / denom;
        float4 bb = ((const float4*)bias)[lane];
        ushort4 o;
        float o0 = a0 * inv + bb.x; o.x = f2b(o0 > 0.f ? o0 : 0.f);
        float o1 = a1 * inv + bb.y; o.y = f2b(o1 > 0.f ? o1 : 0.f);
        float o2 = a2 * inv + bb.z; o.z = f2b(o2 > 0.f ? o2 : 0.f);
        float o3 = a3 * inv + bb.w; o.w = f2b(o3 > 0.f ? o3 : 0.f);
        ((ushort4*)hout)[(size_t)node * 64 + lane] = o;
    }
}

// ---------------- fused layer-3 agg (8 dst nodes) + final conv + LayerNorm + relu ----------------
__global__ __launch_bounds__(256) void k_aggfinal(const unsigned short* __restrict__ hwB,
                                                  const float* __restrict__ sPart, const float* __restrict__ dPart,
                                                  const int* __restrict__ cnt, const int* __restrict__ csr,
                                                  const float* __restrict__ bias,
                                                  const float* __restrict__ wT, const float* __restrict__ tcb,
                                                  const float* __restrict__ g, const float* __restrict__ bln,
                                                  float* __restrict__ out) {
    __shared__ float r01[2][HDIM];
    __shared__ float red[16];
    int b = blockIdx.x, t = threadIdx.x;
    int w = t >> 6, lane = t & 63;
    if (w < 2) {
        int node = b * NSEQ + w;
        int deg = cnt[node];
        const int* bucket = csr + node * CAP;
        float di = dPart[node] + dPart[NTOT + node] + dPart[2 * NTOT + node] + dPart[3 * NTOT + node];
        const ushort4* hw4 = (const ushort4*)hwB;
        float denom = 0.f;
        float a0 = 0.f, a1 = 0.f, a2 = 0.f, a3 = 0.f;
        for (int cb = 0; cb < deg; cb += 64) {
            int j = cb + lane;
            int sj = 0;
            float myw = 0.f;
            if (j < deg) {
                sj = bucket[j];
                float sv = sPart[sj] + sPart[NTOT + sj] + sPart[2 * NTOT + sj] + sPart[3 * NTOT + sj];
                float e = sv + di;
                e = e > 0.f ? e : SLOPE * e;
                myw = __expf(e);
            }
            float csum = myw;
            #pragma unroll
            for (int o = 1; o < 64; o <<= 1) csum += __shfl_xor(csum, o);
            denom += csum;
            int c = deg - cb; if (c > 64) c = 64;
            for (int q = 0; q < c; ++q) {
                int sq = __builtin_amdgcn_readlane(sj, q);
                float wq = rlanef(myw, q);
                ushort4 v = hw4[(size_t)sq * 64 + lane];
                a0 = fmaf(wq, b2f(v.x), a0); a1 = fmaf(wq, b2f(v.y), a1);
                a2 = fmaf(wq, b2f(v.z), a2); a3 = fmaf(wq, b2f(v.w), a3);
            }
        }
        float inv = 1.f / denom;
        float4 bb = ((const float4*)bias)[lane];
        float o0 = a0 * inv + bb.x;
        float o1 = a1 * inv + bb.y;
        float o2 = a2 * inv + bb.z;
        float o3 = a3 * inv + bb.w;
        r01[w][lane * 4 + 0] = o0 > 0.f ? o0 : 0.f;
        r01[w][lane * 4 + 1] = o1 > 0.f ? o1 : 0.f;
        r01[w][lane * 4 + 2] = o2 > 0.f ? o2 : 0.f;
        r01[w][lane * 4 + 3] = o3 > 0.f ? o3 : 0.f;
    }
    __syncthreads();
    int c = t;
    float a = tcb[c];
    for (int f = 0; f < FDIM; ++f) {
        a = fmaf(wT[(1 * FDIM + f) * HDIM + c], r01[0][f], a);
        a = fmaf(wT[(2 * FDIM + f) * HDIM + c], r01[1][f], a);
    }
    float ss = a, sq = a * a;
    #pragma unroll
    for (int o = 1; o < 64; o <<= 1) { ss += __shfl_xor(ss, o); sq += __shfl_xor(sq, o); }
    if (lane == 0) { red[w] = ss; red[8 + w] = sq; }
    __syncthreads();
    float tot = 0.f, totq = 0.f;
    #pragma unroll
    for (int u = 0; u < 4; ++u) { tot += red[u]; totq += red[8 + u]; }
    float mu = tot * (1.f / HDIM);
    float var = totq * (1.f / HDIM) - mu * mu;
    float v = (a - mu) * rsqrtf(var + LN_EPS) * g[c] + bln[c];
    out[b * HDIM + c] = v > 0.f ? v : 0.f;
}

extern "C" void kernel_launch(void* const* d_in, const int* in_sizes, int n_in,
                              void* d_out, int out_size, void* d_ws, size_t ws_size,
                              hipStream_t stream) {
    const float* x     = (const float*)d_in[0];
    const int*   ei    = (const int*)d_in[1];
    const float* tcw   = (const float*)d_in[2];
    const float* tcb   = (const float*)d_in[3];
    const float* gatW  = (const float*)d_in[4];
    const float* gatas = (const float*)d_in[5];
    const float* gatad = (const float*)d_in[6];
    const float* gatb  = (const float*)d_in[7];
    const float* lng   = (const float*)d_in[8];
    const float* lnb   = (const float*)d_in[9];
    float* out = (float*)d_out;

    char* ws = (char*)d_ws;
    unsigned short* hAb = (unsigned short*)(ws + OFF_HA);
    unsigned short* hwB = (unsigned short*)(ws + OFF_HW);
    unsigned short* wcB = (unsigned short*)(ws + OFF_WC);
    unsigned short* WTb = (unsigned short*)(ws + OFF_WL);
    float* sPart = (float*)(ws + OFF_SP);
    float* dPart = (float*)(ws + OFF_DP);
    int*   cnt  = (int*)(ws + OFF_CNT);
    int*   csr  = (int*)(ws + OFF_CSR);
    float* wT   = (float*)(ws + OFF_WT);
    int*   flag1 = (int*)(ws + OFF_F1);
    int*   flag2 = (int*)(ws + OFF_F2);
    int*   list1 = (int*)(ws + OFF_L1);
    int*   list2 = (int*)(ws + OFF_L2);
    int*   ct    = (int*)(ws + OFF_CT);

    k_pre<<<1841, 256, 0, stream>>>(tcw, gatW, wcB, WTb, wT, cnt, flag1, flag2, ct);
    // conv (BM=128 x BN=64) + scatter + S2 build
    k_conv<<<dim3(128 + 272, 4), 256, 0, stream>>>(x, wcB, tcb, hAb, ei, cnt, csr,
                                                   flag2, list2, ct);

    // layer 1: full GEMM + S1 build, then agg over S1
    k_gemm_layer<<<dim3(129, 4), 256, 0, stream>>>(
        hAb, WTb, gatas, gatad, hwB, sPart, dPart,
        cnt, csr, flag1, list1, list2, ct);
    k_agg_list<<<1024, 256, 0, stream>>>(hwB, sPart, dPart, cnt, csr, gatb, hAb, list1, ct + 1);

    // layer 2: GEMM over S1 rows, agg restricted to S2
    k_gemm_list<<<dim3(128, 4), 256, 0, stream>>>(
        hAb, WTb + 65536, gatas + HDIM, gatad + HDIM, hwB, sPart, dPart, list1, ct + 1);
    k_agg_list<<<128, 256, 0, stream>>>(hwB, sPart, dPart, cnt, csr, gatb + HDIM, hAb, list2, ct);

    // layer 3: GEMM over S2 rows, then fused 8-node agg + final conv + LN
    k_gemm_list<<<dim3(4, 4), 256, 0, stream>>>(
        hAb, WTb + 131072, gatas + 2 * HDIM, gatad + 2 * HDIM, hwB, sPart, dPart, list2, ct);
    k_aggfinal<<<BBATCH, 256, 0, stream>>>(hwB, sPart, dPart, cnt, csr, gatb + 2 * HDIM,
                                           wT, tcb, lng, lnb, out);
}